// Round 1
// baseline (155.668 us; speedup 1.0000x reference)
//
#include <hip/hip_runtime.h>

#define F_DIM 225
#define G_DIM 15
#define I_DIM 15
#define H_DIM 5
#define NOUT  75
#define ROWS  16
#define THREADS 256

__global__ __launch_bounds__(THREADS) void mlp_rsna_kernel(
    const float* __restrict__ x,
    const float* __restrict__ w1,
    const float* __restrict__ b1,
    const float* __restrict__ w2,
    const float* __restrict__ b2,
    const int* __restrict__ k_idx,
    const int* __restrict__ v_idx,
    float* __restrict__ out,
    int B)
{
    // LDS: 14400 + 4800 + small tables ~= 20.6 KB -> 7 blocks/CU (28 waves)
    __shared__ __align__(16) float x_lds[ROWS * F_DIM];   // 3600 f32
    __shared__ __align__(16) float o_lds[ROWS * NOUT];    // 1200 f32
    __shared__ float w1_lds[H_DIM * I_DIM];
    __shared__ float b1_lds[H_DIM];
    __shared__ float w2_lds[H_DIM * H_DIM];
    __shared__ float b2_lds[H_DIM];
    __shared__ int   k_lds[G_DIM * I_DIM];
    __shared__ int   v_lds[G_DIM * H_DIM];

    const int tid = threadIdx.x;
    const int block_row0 = (int)blockIdx.x * ROWS;
    const int rows_here = min(ROWS, B - block_row0);

    // ---- stage weights / indices (tiny, L2-hit) ----
    if (tid < H_DIM * I_DIM) w1_lds[tid] = w1[tid];
    if (tid < H_DIM)         b1_lds[tid] = b1[tid];
    if (tid < H_DIM * H_DIM) w2_lds[tid] = w2[tid];
    if (tid < H_DIM)         b2_lds[tid] = b2[tid];
    if (tid < G_DIM * I_DIM) k_lds[tid] = k_idx[tid];
    if (tid < G_DIM * H_DIM) v_lds[tid] = v_idx[tid];

    // ---- stage x rows: coalesced float4 (16*225*4 B = 14400 B, 16B-aligned) ----
    if (rows_here == ROWS) {
        const float4* src4 = reinterpret_cast<const float4*>(x + (size_t)block_row0 * F_DIM);
        float4* xl4 = reinterpret_cast<float4*>(x_lds);
        #pragma unroll
        for (int k = 0; k < 4; ++k) {
            int idx = tid + k * THREADS;
            if (idx < ROWS * F_DIM / 4) xl4[idx] = src4[idx];
        }
    } else {
        const float* src = x + (size_t)block_row0 * F_DIM;
        for (int k = tid; k < rows_here * F_DIM; k += THREADS) x_lds[k] = src[k];
    }

    // ---- zero the output tile (reference semantics: zeros + scatter) ----
    for (int k = tid; k < ROWS * NOUT; k += THREADS) o_lds[k] = 0.0f;

    __syncthreads();

    // ---- compute: one thread per (row, group); 240 active ----
    if (tid < rows_here * G_DIM) {
        const int r = tid / G_DIM;
        const int g = tid - r * G_DIM;
        const float* xr = &x_lds[r * F_DIM];

        float xv[I_DIM];
        #pragma unroll
        for (int i = 0; i < I_DIM; ++i) xv[i] = xr[k_lds[g * I_DIM + i]];

        float hv[H_DIM];
        #pragma unroll
        for (int hh = 0; hh < H_DIM; ++hh) {
            float acc = b1_lds[hh];
            #pragma unroll
            for (int i = 0; i < I_DIM; ++i) acc += xv[i] * w1_lds[hh * I_DIM + i];
            hv[hh] = fmaxf(acc, 0.0f);
        }
        #pragma unroll
        for (int oo = 0; oo < H_DIM; ++oo) {
            float acc = b2_lds[oo];
            #pragma unroll
            for (int hh = 0; hh < H_DIM; ++hh) acc += hv[hh] * w2_lds[oo * H_DIM + hh];
            o_lds[r * NOUT + v_lds[g * H_DIM + oo]] = acc;
        }
    }

    __syncthreads();

    // ---- coalesced float4 writeback (16*75*4 B = 4800 B, 16B-aligned) ----
    if (rows_here == ROWS) {
        float4* dst4 = reinterpret_cast<float4*>(out + (size_t)block_row0 * NOUT);
        const float4* ol4 = reinterpret_cast<const float4*>(o_lds);
        for (int k = tid; k < ROWS * NOUT / 4; k += THREADS) dst4[k] = ol4[k];
    } else {
        float* dst = out + (size_t)block_row0 * NOUT;
        for (int k = tid; k < rows_here * NOUT; k += THREADS) dst[k] = o_lds[k];
    }
}

extern "C" void kernel_launch(void* const* d_in, const int* in_sizes, int n_in,
                              void* d_out, int out_size, void* d_ws, size_t ws_size,
                              hipStream_t stream) {
    const float* x     = (const float*)d_in[0];
    const float* w1    = (const float*)d_in[1];
    const float* b1    = (const float*)d_in[2];
    const float* w2    = (const float*)d_in[3];
    const float* b2    = (const float*)d_in[4];
    const int*   k_idx = (const int*)d_in[5];
    const int*   v_idx = (const int*)d_in[6];
    float* out = (float*)d_out;

    const int B = in_sizes[0] / F_DIM;
    const int grid = (B + ROWS - 1) / ROWS;
    mlp_rsna_kernel<<<grid, THREADS, 0, stream>>>(x, w1, b1, w2, b2, k_idx, v_idx, out, B);
}

// Round 3
// 142.947 us; speedup vs baseline: 1.0890x; 1.0890x over previous
//
#include <hip/hip_runtime.h>

#define F_DIM 225
#define G_DIM 15
#define I_DIM 15
#define H_DIM 5
#define NOUT  75
#define ROWS  16
#define THREADS 256
#define TILE_F4 ((ROWS * F_DIM) / 4)   // 900 float4 = 14400 B per tile

__global__ __launch_bounds__(THREADS) void mlp_rsna_kernel(
    const float* __restrict__ x,
    const float* __restrict__ w1, const float* __restrict__ b1,
    const float* __restrict__ w2, const float* __restrict__ b2,
    const int* __restrict__ k_idx, const int* __restrict__ v_idx,
    float* __restrict__ out, int B)
{
    // LDS: 14.4 KB x-tile + small idx tables -> occupancy capped by waves (8 blocks/CU)
    __shared__ __align__(16) float x_lds[ROWS * F_DIM];   // 3600 f32
    __shared__ int k_lds[G_DIM * I_DIM];                  // 225
    __shared__ int v_lds[G_DIM * H_DIM];                  // 75

    const int tid = threadIdx.x;
    const int block_row0 = (int)blockIdx.x * ROWS;
    const int rows_here = min(ROWS, B - block_row0);

    // ---- stage idx tables (tiny, L2-hit) ----
    if (tid < G_DIM * I_DIM) k_lds[tid] = k_idx[tid];
    if (tid < G_DIM * H_DIM) v_lds[tid] = v_idx[tid];

    // ---- stage x rows: coalesced float4 -> LDS (R1-proven path) ----
    if (rows_here == ROWS) {
        const float4* src4 = reinterpret_cast<const float4*>(x + (size_t)block_row0 * F_DIM);
        float4* xl4 = reinterpret_cast<float4*>(x_lds);
#pragma unroll
        for (int k = 0; k < 4; ++k) {
            int idx = tid + k * THREADS;
            if (idx < TILE_F4) xl4[idx] = src4[idx];
        }
    } else {
        const float* src = x + (size_t)block_row0 * F_DIM;
        for (int k = tid; k < rows_here * F_DIM; k += THREADS) x_lds[k] = src[k];
    }

    __syncthreads();

    // ---- compute: one thread per (row, group); weights via uniform/scalar loads ----
    if (tid < rows_here * G_DIM) {
        const int r = tid / G_DIM;
        const int g = tid - r * G_DIM;
        const float* xr = &x_lds[r * F_DIM];

        float xv[I_DIM];
#pragma unroll
        for (int i = 0; i < I_DIM; ++i) xv[i] = xr[k_lds[g * I_DIM + i]];

        float hv[H_DIM];
#pragma unroll
        for (int hh = 0; hh < H_DIM; ++hh) {
            float acc = b1[hh];                              // uniform addr -> s_load/K$
#pragma unroll
            for (int i = 0; i < I_DIM; ++i)
                acc = fmaf(xv[i], w1[hh * I_DIM + i], acc);  // uniform addr -> s_load/K$
            hv[hh] = fmaxf(acc, 0.0f);
        }

        float* orow = out + ((size_t)block_row0 + r) * NOUT;
#pragma unroll
        for (int oo = 0; oo < H_DIM; ++oo) {
            float acc = b2[oo];
#pragma unroll
            for (int hh = 0; hh < H_DIM; ++hh)
                acc = fmaf(hv[hh], w2[oo * H_DIM + hh], acc);
            orow[v_lds[g * H_DIM + oo]] = acc;               // direct scatter store
        }
    }
}

extern "C" void kernel_launch(void* const* d_in, const int* in_sizes, int n_in,
                              void* d_out, int out_size, void* d_ws, size_t ws_size,
                              hipStream_t stream) {
    const float* x     = (const float*)d_in[0];
    const float* w1    = (const float*)d_in[1];
    const float* b1    = (const float*)d_in[2];
    const float* w2    = (const float*)d_in[3];
    const float* b2    = (const float*)d_in[4];
    const int*   k_idx = (const int*)d_in[5];
    const int*   v_idx = (const int*)d_in[6];
    float* out = (float*)d_out;

    const int B = in_sizes[0] / F_DIM;
    const int grid = (B + ROWS - 1) / ROWS;
    mlp_rsna_kernel<<<grid, THREADS, 0, stream>>>(x, w1, b1, w2, b2, k_idx, v_idx, out, B);
}